// Round 4
// baseline (122.017 us; speedup 1.0000x reference)
//
#include <hip/hip_runtime.h>
#include <stdint.h>

#define B_    32
#define H_    640
#define W_    368
#define OH    634          // H - 6
#define OW    362          // W - 6
#define CHUNK 10           // output rows per block
#define NCHUNK 64          // 63 full chunks + last (4 rows); 63*10+4 = 634
#define NBLK  (NCHUNK * B_)          // 2048 = 8 blocks/CU exactly (1 round at 24 waves/CU)
#define GROUPS 64

// d_ws layout (floats):
//   [0..31]      per-batch max of target (int-bits atomicMax; 0xAA poison is negative,
//                any positive-float bits win, so no pre-zeroing needed)
//   [64..1087]   64 partial-sum slots, stride 16 floats (64 B); zeroed by k_max blk 0
//
// R1/R2 lesson: do NOT fuse the final reduction into k_ssim with a last-block-done
// pattern: the device-scope __threadfence() costs ~70 ns serialized per block
// (2048 blocks -> +110 us). Separate 3 us k_fin dispatch is far cheaper.
#define SLOT0 64
#define STRIDE 16

typedef float f2 __attribute__((ext_vector_type(2)));

__global__ __launch_bounds__(256) void k_max(const float* __restrict__ tgt,
                                             float* __restrict__ ws) {
    if (blockIdx.x == 0) {                     // zero slots (stream order vs k_ssim)
        for (int i = threadIdx.x; i < GROUPS * STRIDE; i += 256)
            ws[SLOT0 + i] = 0.0f;
    }
    const int b   = blockIdx.x >> 5;
    const int seg = blockIdx.x & 31;
    const int perseg = (H_ * W_) / 32;         // 7360 floats
    const float4* p = (const float4*)(tgt + (size_t)b * (H_ * W_) + (size_t)seg * perseg);
    const int n4 = perseg / 4;                 // 1840
    float m = 0.0f;
    for (int i = threadIdx.x; i < n4; i += 256) {
        float4 v = p[i];
        m = fmaxf(m, fmaxf(fmaxf(v.x, v.y), fmaxf(v.z, v.w)));
    }
    #pragma unroll
    for (int off = 32; off; off >>= 1)
        m = fmaxf(m, __shfl_down(m, off, 64));
    __shared__ float sm[4];
    const int lane = threadIdx.x & 63, wv = threadIdx.x >> 6;
    if (lane == 0) sm[wv] = m;
    __syncthreads();
    if (threadIdx.x == 0) {
        m = fmaxf(fmaxf(sm[0], sm[1]), fmaxf(sm[2], sm[3]));
        atomicMax((int*)ws + b, __float_as_int(m));   // inputs >= 0
    }
}

// Async-stage one (X,Y) row pair into LDS. Row = 368 floats = 1472 B = 92 x 16 B.
// global_load_lds: LDS dest is wave-uniform base + lane*16 (m104), global src per-lane.
//   wave 0: X bytes [0,1024)     (64 lanes)
//   wave 1: Y bytes [0,1024)     (64 lanes)
//   wave 2: X,Y bytes [1024,1472) (lanes 0..27, exec-masked)
__device__ __forceinline__ void stage_row(const float* __restrict__ Xr,
                                          const float* __restrict__ Yr,
                                          float* ldsX, float* ldsY,
                                          int w, int lane) {
    if (w == 0) {
        __builtin_amdgcn_global_load_lds(
            (const __attribute__((address_space(1))) void*)(Xr + lane * 4),
            (__attribute__((address_space(3))) void*)(ldsX), 16, 0, 0);
    } else if (w == 1) {
        __builtin_amdgcn_global_load_lds(
            (const __attribute__((address_space(1))) void*)(Yr + lane * 4),
            (__attribute__((address_space(3))) void*)(ldsY), 16, 0, 0);
    } else if (lane < 28) {
        __builtin_amdgcn_global_load_lds(
            (const __attribute__((address_space(1))) void*)(Xr + 256 + lane * 4),
            (__attribute__((address_space(3))) void*)(ldsX + 256), 16, 0, 0);
        __builtin_amdgcn_global_load_lds(
            (const __attribute__((address_space(1))) void*)(Yr + 256 + lane * 4),
            (__attribute__((address_space(3))) void*)(ldsY + 256), 16, 0, 0);
    }
}

// Horizontal 7-sums for TWO adjacent windows (cols c..c+6, c+1..c+7) from
// preloaded registers.  h = {x0,x1, y0,y1, s0,s1 (xx+yy), xy0,xy1}
// SSIM only ever consumes txx+tyy, so xx and yy share ONE accumulator (ring 4q).
__device__ __forceinline__ void hsum2v(const f2 xn[4], const f2 yn[4], float h[8]) {
    const float xs[8] = {xn[0].x, xn[0].y, xn[1].x, xn[1].y, xn[2].x, xn[2].y, xn[3].x, xn[3].y};
    const float ys[8] = {yn[0].x, yn[0].y, yn[1].x, yn[1].y, yn[2].x, yn[2].y, yn[3].x, yn[3].y};
    float hx = 0, hy = 0, hs = 0, hxy = 0;
    #pragma unroll
    for (int k = 0; k < 7; ++k) {
        const float xv = xs[k], yv = ys[k];
        hx += xv; hy += yv;
        hs  = fmaf(xv, xv, hs);
        hs  = fmaf(yv, yv, hs);
        hxy = fmaf(xv, yv, hxy);
    }
    h[0] = hx;  h[1] = hx - xs[0] + xs[7];
    h[2] = hy;  h[3] = hy - ys[0] + ys[7];
    h[4] = hs;
    h[5] = fmaf(xs[7], xs[7], fmaf(ys[7], ys[7], fmaf(-xs[0], xs[0], fmaf(-ys[0], ys[0], hs))));
    h[6] = hxy; h[7] = fmaf(xs[7], ys[7], fmaf(-xs[0], ys[0], hxy));
}

__device__ __forceinline__ void loadlds(const float* bx, const float* by,
                                        int c, f2 xn[4], f2 yn[4]) {
    const f2* xp = (const f2*)(bx + c);   // 8B-aligned -> ds_read_b64 x4
    const f2* yp = (const f2*)(by + c);
    xn[0] = xp[0]; xn[1] = xp[1]; xn[2] = xp[2]; xn[3] = xp[3];
    yn[0] = yp[0]; yn[1] = yp[1]; yn[2] = yp[2]; yn[3] = yp[3];
}

// R3->R4: rows staged ONCE per block into a 3-slot LDS ring via global_load_lds
// (2 wave-instrs/row vs 24 dwordx2: kills the 4x L1 read amplification of the
// private 8-float windows). __syncthreads per row is fine: its vmcnt(0) drain
// stalls only this block; the other 7 blocks/CU keep the SIMDs fed (m114).
__global__ __launch_bounds__(192) void k_ssim(const float* __restrict__ X,
                                              const float* __restrict__ Y,
                                              float* __restrict__ ws) {
    const int t    = threadIdx.x;              // 0..191
    const int w    = t >> 6;
    const int lane = t & 63;
    const int b    = blockIdx.y;
    const int r0   = blockIdx.x * CHUNK;
    const int outRows = min(CHUNK, OH - r0);   // 10, or 4 for last chunk
    const int nrows   = outRows + 6;           // rows touched by this block
    const int c    = 2 * t;                    // base output col
    const bool colOK = (c < OW);               // t <= 180

    __shared__ float bufX[3][384];             // 3-slot row ring, 1536 B/slot (1472 used)
    __shared__ float bufY[3][384];             // total 9.2 KB/block; 8 blk/CU = 74 KB

    const float dr  = ws[b];
    float C1 = 0.01f * dr; C1 *= C1;
    float C2 = 0.03f * dr; C2 *= C2;
    const float c1s = C1 * 2401.0f;            // scaled-domain constants (u* scale cancels)
    const float c2s = C2 * 2401.0f;
    const float covn2 = 2.0f * (49.0f / 48.0f);
    const float covn  = 49.0f / 48.0f;

    const float* Xb = X + (size_t)b * (H_ * W_);
    const float* Yb = Y + (size_t)b * (H_ * W_);

    // prologue: stage rows r0, r0+1 into slots 0,1 (disjoint LDS, no barrier needed)
    stage_row(Xb + (size_t)r0 * W_,       Yb + (size_t)r0 * W_,       bufX[0], bufY[0], w, lane);
    stage_row(Xb + (size_t)(r0 + 1) * W_, Yb + (size_t)(r0 + 1) * W_, bufX[1], bufY[1], w, lane);

    int nstaged = 2;
    int ss = 2;                                // next stage slot
    int cs = 0;                                // next consume slot

    float acc = 0.0f;
    float ring[4][7][2];                       // [quantity][row slot][col] — compile-time idx
    float tot[4][2] = {};
    float h[8];
    f2 xn[4], yn[4];

    #pragma unroll
    for (int p = 0; p < 6; ++p) {              // prime 6 halo rows
        __syncthreads();                       // staged(<=p+1) complete; slot ss free
        if (nstaged < nrows) {
            stage_row(Xb + (size_t)(r0 + nstaged) * W_, Yb + (size_t)(r0 + nstaged) * W_,
                      bufX[ss], bufY[ss], w, lane);
            ++nstaged; ss = (ss == 2) ? 0 : ss + 1;
        }
        if (colOK) {
            loadlds(bufX[cs], bufY[cs], c, xn, yn);
            hsum2v(xn, yn, h);
            #pragma unroll
            for (int q = 0; q < 4; ++q) {
                ring[q][p][0] = h[2 * q];     ring[q][p][1] = h[2 * q + 1];
                tot[q][0] += h[2 * q];        tot[q][1] += h[2 * q + 1];
            }
        }
        cs = (cs == 2) ? 0 : cs + 1;
    }

    for (int ii = 0; ii < outRows; ii += 7) {
        #pragma unroll
        for (int p = 0; p < 7; ++p) {          // ring slot == p (compile-time)
            const int i = ii + p;
            if (i >= outRows) break;           // block-uniform
            __syncthreads();
            if (nstaged < nrows) {
                stage_row(Xb + (size_t)(r0 + nstaged) * W_, Yb + (size_t)(r0 + nstaged) * W_,
                          bufX[ss], bufY[ss], w, lane);
                ++nstaged; ss = (ss == 2) ? 0 : ss + 1;
            }
            if (colOK) {
                loadlds(bufX[cs], bufY[cs], c, xn, yn);   // row r0+i+6
                hsum2v(xn, yn, h);

                #pragma unroll
                for (int q = 0; q < 4; ++q) {
                    tot[q][0] += h[2 * q];    tot[q][1] += h[2 * q + 1];
                }

                #pragma unroll
                for (int j = 0; j < 2; ++j) {
                    const float tx = tot[0][j], ty = tot[1][j];
                    const float ts = tot[2][j], txy = tot[3][j];
                    const float pxy = tx * ty;
                    const float A1  = fmaf(pxy, 2.0f, c1s);
                    const float s2  = fmaf(tx, tx, ty * ty);
                    const float B1  = s2 + c1s;
                    const float mxy = fmaf(49.0f, txy, -pxy);
                    const float A2  = fmaf(covn2, mxy, c2s);
                    const float vs  = fmaf(49.0f, ts, -s2);
                    const float B2  = fmaf(covn, vs, c2s);
                    acc = fmaf(A1 * A2, __builtin_amdgcn_rcpf(B1 * B2), acc);
                }

                const int sn = (p + 6) % 7;    // retire slot p, insert new in slot sn
                #pragma unroll
                for (int q = 0; q < 4; ++q) {
                    tot[q][0] -= ring[q][p][0];  tot[q][1] -= ring[q][p][1];
                    ring[q][sn][0] = h[2 * q];   ring[q][sn][1] = h[2 * q + 1];
                }
            }
            cs = (cs == 2) ? 0 : cs + 1;
        }
    }

    // wave reduce, LDS across 3 waves, ONE scattered atomic per block. No fences!
    #pragma unroll
    for (int off = 32; off; off >>= 1)
        acc += __shfl_down(acc, off, 64);
    __shared__ float sm[3];
    if (lane == 0) sm[w] = acc;
    __syncthreads();
    if (t == 0) {
        const float s = sm[0] + sm[1] + sm[2];
        const int blk = blockIdx.y * NCHUNK + blockIdx.x;
        atomicAdd(ws + SLOT0 + (blk & (GROUPS - 1)) * STRIDE, s);  // 64 independent lines
    }
}

__global__ __launch_bounds__(64) void k_fin(const float* __restrict__ ws,
                                            float* __restrict__ out) {
    float v = ws[SLOT0 + threadIdx.x * STRIDE];   // kernel boundary orders prior atomics
    #pragma unroll
    for (int off = 32; off; off >>= 1)
        v += __shfl_down(v, off, 64);
    if (threadIdx.x == 0)
        out[0] = 1.0f - v * (1.0f / (32.0f * 634.0f * 362.0f));
}

extern "C" void kernel_launch(void* const* d_in, const int* in_sizes, int n_in,
                              void* d_out, int out_size, void* d_ws, size_t ws_size,
                              hipStream_t stream) {
    const float* X = (const float*)d_in[0];   // 'output'
    const float* Y = (const float*)d_in[1];   // 'target'
    float* ws = (float*)d_ws;

    k_max<<<dim3(1024), dim3(256), 0, stream>>>(Y, ws);
    k_ssim<<<dim3(NCHUNK, B_), dim3(192), 0, stream>>>(X, Y, ws);
    k_fin<<<dim3(1), dim3(64), 0, stream>>>(ws, (float*)d_out);
}